// Round 8
// baseline (116.275 us; speedup 1.0000x reference)
//
#include <hip/hip_runtime.h>

#define SB 8
#define SS 2048
#define SD 1024
#define SH 64

typedef float f32x4 __attribute__((ext_vector_type(4)));
typedef __bf16 bf16x8 __attribute__((ext_vector_type(8)));

__device__ __forceinline__ unsigned short f2bf(float f) {
  union { float f; unsigned int u; } v; v.f = f;
  unsigned int u = v.u;
  unsigned int r = u + 0x7FFFu + ((u >> 16) & 1u);
  return (unsigned short)(r >> 16);
}

// Wt[hc][d] = W_{hc/64}[d][hc&63] as bf16, hc in [0,192), d in [0,1024)
__global__ void prep_wt(const float* __restrict__ Wq, const float* __restrict__ Wk,
                        const float* __restrict__ Wv, unsigned short* __restrict__ Wt) {
  int idx = blockIdx.x * 256 + threadIdx.x;
  int hc = idx >> 10, d = idx & 1023;
  const float* W = (hc < 64) ? Wq : (hc < 128) ? Wk : Wv;
  int h = hc & 63;
  Wt[idx] = f2bf(W[d * SH + h]);
}

// QKV projection (round-3 proven structure, ~37us): M=16384, N=192, K=1024.
// 256 blocks x 512 thr. Block = 64 rows x 192 cols; wave = 32 rows x 48 cols.
__global__ void __launch_bounds__(512, 2) proj(
    const float* __restrict__ x, const unsigned short* __restrict__ Wt,
    unsigned short* __restrict__ Q, unsigned short* __restrict__ K,
    unsigned short* __restrict__ Vt) {
  __shared__ unsigned short xs[64 * 64];  // 8 KB, cg ^= (row&7) swizzle

  int tid = threadIdx.x;
  int w = tid >> 6, lane = tid & 63;
  int l15 = lane & 15, kg = lane >> 4;
  int wr = w >> 2, wc = w & 3;
  int m0 = blockIdx.x * 64;

  int srow = tid >> 3, sseg = tid & 7;
  const float* xp = x + (size_t)(m0 + srow) * SD + sseg * 8;
  unsigned short* swp = xs + srow * 64 + ((sseg ^ (srow & 7)) * 8);

  float4 ra = *(const float4*)xp;
  float4 rb = *(const float4*)(xp + 4);

  f32x4 acc[2][3];
#pragma unroll
  for (int mt = 0; mt < 2; ++mt)
#pragma unroll
    for (int nt = 0; nt < 3; ++nt) acc[mt][nt] = f32x4{0.f, 0.f, 0.f, 0.f};

  for (int t = 0; t < 16; ++t) {
    union { unsigned short us[8]; bf16x8 v; } cv;
    cv.us[0] = f2bf(ra.x); cv.us[1] = f2bf(ra.y);
    cv.us[2] = f2bf(ra.z); cv.us[3] = f2bf(ra.w);
    cv.us[4] = f2bf(rb.x); cv.us[5] = f2bf(rb.y);
    cv.us[6] = f2bf(rb.z); cv.us[7] = f2bf(rb.w);
    *(bf16x8*)swp = cv.v;
    __syncthreads();

    if (t < 15) {
      ra = *(const float4*)(xp + (t + 1) * 64);
      rb = *(const float4*)(xp + (t + 1) * 64 + 4);
    }

    int k0 = t * 64;
#pragma unroll
    for (int ks = 0; ks < 2; ++ks) {
      bf16x8 af[2];
#pragma unroll
      for (int mt = 0; mt < 2; ++mt) {
        int row = wr * 32 + mt * 16 + l15;
        int cg = ks * 4 + kg;
        af[mt] = *(const bf16x8*)(xs + row * 64 + ((cg ^ (row & 7)) * 8));
      }
#pragma unroll
      for (int nt = 0; nt < 3; ++nt) {
        int c = wc * 48 + nt * 16 + l15;
        bf16x8 bfr = *(const bf16x8*)(Wt + (size_t)c * SD + k0 + ks * 32 + kg * 8);
#pragma unroll
        for (int mt = 0; mt < 2; ++mt)
          acc[mt][nt] = __builtin_amdgcn_mfma_f32_16x16x32_bf16(af[mt], bfr, acc[mt][nt], 0, 0, 0);
      }
    }
    __syncthreads();
  }

#pragma unroll
  for (int nt = 0; nt < 3; ++nt) {
    int c = wc * 48 + nt * 16 + l15;
    int mat = c >> 6, h = c & 63;
#pragma unroll
    for (int mt = 0; mt < 2; ++mt)
#pragma unroll
      for (int r = 0; r < 4; ++r) {
        int row = m0 + wr * 32 + mt * 16 + kg * 4 + r;
        unsigned short bv = f2bf(acc[mt][nt][r]);
        if (mat == 0) {
          Q[(size_t)row * SH + h] = bv;
        } else if (mat == 1) {
          K[(size_t)row * SH + h] = bv;
        } else {
          int bb = row >> 11, key = row & 2047;
          Vt[((size_t)bb * SH + h) * SS + key] = bv;
        }
      }
  }
}

// Attention, single pass, KV-split x8, swapped QK^T.
// KEY CHANGE vs r7: phase C (PV) has ZERO global stores; phase D does all
// weight stores afterwards. vmcnt decrements in issue order, so stores issued
// before loads force every load-wait to drain them (~600-900cy HBM ack) --
// deferring stores past the last load removes 4 serialized drain stalls/wave.
// 1024 blocks x 512 thr, 35.8 KB LDS -> 4 blocks/CU.
__global__ void __launch_bounds__(512, 4) attn(
    const unsigned short* __restrict__ Q, const unsigned short* __restrict__ Kb,
    const unsigned short* __restrict__ Vt, float* __restrict__ out,
    float* __restrict__ wts) {
  __shared__ __align__(16) float pf[8][16][68];  // 34.8 KB, per-wave slices
  __shared__ float mS[8][16], sgS[8][16];

  int b = blockIdx.x & 7, rg = blockIdx.x >> 3;
  int w = threadIdx.x >> 6, lane = threadIdx.x & 63;
  int l15 = lane & 15, kg = lane >> 4;
  int q0 = rg * 16;
  int kv0 = w * 256;

  const unsigned short* Qb  = Q  + (size_t)b * SS * SH;
  const unsigned short* Kbb = Kb + (size_t)b * SS * SH;
  const unsigned short* Vtb = Vt + (size_t)b * SH * SS;

  bf16x8 qf[2];
#pragma unroll
  for (int ks = 0; ks < 2; ++ks)
    qf[ks] = *(const bf16x8*)(Qb + (size_t)(q0 + l15) * SH + ks * 32 + kg * 8);

  // ---- phase A: QK^T (swapped): s[kt][n][r] = S[k=kv0+kt*64+n*16+kg*4+r][q=q0+l15]
  f32x4 s[4][4];
#pragma unroll
  for (int kt = 0; kt < 4; ++kt)
#pragma unroll
    for (int n = 0; n < 4; ++n) s[kt][n] = f32x4{0.f, 0.f, 0.f, 0.f};

  for (int kt = 0; kt < 4; ++kt) {
#pragma unroll
    for (int ks = 0; ks < 2; ++ks)
#pragma unroll
      for (int n = 0; n < 4; ++n) {
        bf16x8 kf = *(const bf16x8*)(Kbb + (size_t)(kv0 + kt * 64 + n * 16 + l15) * SH + ks * 32 + kg * 8);
        s[kt][n] = __builtin_amdgcn_mfma_f32_16x16x32_bf16(kf, qf[ks], s[kt][n], 0, 0, 0);
      }
  }

  // ---- phase B: softmax stats; lane owns one q-row, 64 k-values
  float mloc = -1e30f;
#pragma unroll
  for (int kt = 0; kt < 4; ++kt)
#pragma unroll
    for (int n = 0; n < 4; ++n)
#pragma unroll
      for (int r = 0; r < 4; ++r) mloc = fmaxf(mloc, s[kt][n][r]);
  mloc *= 0.125f;
  mloc = fmaxf(mloc, __shfl_xor(mloc, 16));
  mloc = fmaxf(mloc, __shfl_xor(mloc, 32));

  float ssum = 0.f;
#pragma unroll
  for (int kt = 0; kt < 4; ++kt)
#pragma unroll
    for (int n = 0; n < 4; ++n)
#pragma unroll
      for (int r = 0; r < 4; ++r) {
        float e = __expf(s[kt][n][r] * 0.125f - mloc);
        s[kt][n][r] = e;
        ssum += e;
      }
  ssum += __shfl_xor(ssum, 16);
  ssum += __shfl_xor(ssum, 32);

  if (lane < 16) {
    mS[w][l15] = mloc;
    sgS[w][l15] = ssum;
  }
  __syncthreads();

  float M = -1e30f;
#pragma unroll
  for (int ww = 0; ww < 8; ++ww) M = fmaxf(M, mS[ww][l15]);
  float Sg = 0.f;
#pragma unroll
  for (int ww = 0; ww < 8; ++ww) Sg += sgS[ww][l15] * __expf(mS[ww][l15] - M);
  float scal = __expf(mloc - M) / Sg;

  f32x4 oacc[4];
#pragma unroll
  for (int nh = 0; nh < 4; ++nh) oacc[nh] = f32x4{0.f, 0.f, 0.f, 0.f};

  // ---- phase C: PV only, NO global stores (keeps vmcnt clean for vf loads)
  for (int kt = 0; kt < 4; ++kt) {
#pragma unroll
    for (int n = 0; n < 4; ++n) {
      f32x4 pv;
#pragma unroll
      for (int r = 0; r < 4; ++r) pv[r] = s[kt][n][r] * scal;
      *(f32x4*)&pf[w][l15][n * 16 + kg * 4] = pv;
    }

#pragma unroll
    for (int ks = 0; ks < 2; ++ks) {
      f32x4 pa = *(const f32x4*)&pf[w][l15][ks * 32 + kg * 8];
      f32x4 pb = *(const f32x4*)&pf[w][l15][ks * 32 + kg * 8 + 4];
      union { unsigned short us[8]; bf16x8 v; } pu;
#pragma unroll
      for (int i = 0; i < 4; ++i) { pu.us[i] = f2bf(pa[i]); pu.us[4 + i] = f2bf(pb[i]); }
#pragma unroll
      for (int nh = 0; nh < 4; ++nh) {
        bf16x8 vf = *(const bf16x8*)(Vtb + (size_t)(nh * 16 + l15) * SS + kv0 + kt * 64 + ks * 32 + kg * 8);
        oacc[nh] = __builtin_amdgcn_mfma_f32_16x16x32_bf16(pu.v, vf, oacc[nh], 0, 0, 0);
      }
    }
  }

  // ---- phase D: all weight stores (no loads follow -> drains never block)
  float* wtp = wts + (size_t)b * SS * SS + (size_t)q0 * SS + kv0;
  for (int kt = 0; kt < 4; ++kt) {
#pragma unroll
    for (int n = 0; n < 4; ++n) {
      f32x4 pv;
#pragma unroll
      for (int r = 0; r < 4; ++r) pv[r] = s[kt][n][r] * scal;
      *(f32x4*)&pf[w][l15][n * 16 + kg * 4] = pv;
    }
#pragma unroll
    for (int i = 0; i < 4; ++i) {
      int row = i * 4 + kg;
      f32x4 pv4 = *(const f32x4*)&pf[w][row][l15 * 4];
      *(f32x4*)(wtp + (size_t)row * SS + kt * 64 + l15 * 4) = pv4;
    }
  }

  // ---- combine partial PV across the 8 waves (pf reused after barrier)
  __syncthreads();
#pragma unroll
  for (int nh = 0; nh < 4; ++nh)
#pragma unroll
    for (int r = 0; r < 4; ++r)
      pf[w][kg * 4 + r][nh * 16 + l15] = oacc[nh][r];
  __syncthreads();

  int tid = threadIdx.x;
#pragma unroll
  for (int half = 0; half < 2; ++half) {
    int e = tid + half * 512;
    int row = e >> 6, col = e & 63;
    float ssum2 = 0.f;
#pragma unroll
    for (int ww = 0; ww < 8; ++ww) ssum2 += pf[ww][row][col];
    out[((size_t)b * SS + q0 + row) * SH + col] = ssum2;
  }
}

extern "C" void kernel_launch(void* const* d_in, const int* in_sizes, int n_in,
                              void* d_out, int out_size, void* d_ws, size_t ws_size,
                              hipStream_t stream) {
  const float* x  = (const float*)d_in[0];
  const float* Wq = (const float*)d_in[1];
  const float* Wk = (const float*)d_in[2];
  const float* Wv = (const float*)d_in[3];

  unsigned short* Wt = (unsigned short*)d_ws;                 // 192*1024
  unsigned short* Q  = Wt + 192 * 1024;                       // 16384*64
  unsigned short* K  = Q + 16384 * 64;                        // 16384*64
  unsigned short* Vt = K + 16384 * 64;                        // 8*64*2048

  float* out = (float*)d_out;
  float* wts = out + (size_t)SB * SS * SH;

  prep_wt<<<768, 256, 0, stream>>>(Wq, Wk, Wv, Wt);
  proj<<<256, 512, 0, stream>>>(x, Wt, Q, K, Vt);
  attn<<<1024, 512, 0, stream>>>(Q, K, Vt, out, wts);
}